// Round 3
// baseline (137.222 us; speedup 1.0000x reference)
//
#include <hip/hip_runtime.h>

// out[i] = sum_{j=0..9} in[10*i + j] * (j+1)/55   (stride==d==10 -> windows tile T exactly)
//
// Coalescing via LDS bounce:
//  - each wave-iteration handles 320 contiguous float4 = 1280 floats = 128 windows
//  - 5 lane-contiguous float4 global loads (perfectly coalesced, 16B/lane)
//  - ds_write_b128 lane-contiguous (conflict-free)
//  - ds_read_b128 at 80B stride: lanes 0..7 hit all 32 banks exactly once -> conflict-free
//  - __syncthreads() both after stage and after consume: cross-lane LDS exchange
//    requires a barrier for COMPILER ordering (R2 failed without it).

__global__ __launch_bounds__(256) void ts_decaylinear_kernel(
    const float4* __restrict__ in4, float2* __restrict__ out2, long long nChunks) {

    __shared__ float lds[4 * 1280];  // 4 waves x 1280 floats = 20 KB
    const int wave = threadIdx.x >> 6;
    const int lane = threadIdx.x & 63;
    float4* l4 = reinterpret_cast<float4*>(&lds[wave * 1280]);

    const float w0 = 1.0f / 55.0f, w1 = 2.0f / 55.0f, w2 = 3.0f / 55.0f,
                w3 = 4.0f / 55.0f, w4 = 5.0f / 55.0f, w5 = 6.0f / 55.0f,
                w6 = 7.0f / 55.0f, w7 = 8.0f / 55.0f, w8 = 9.0f / 55.0f,
                w9 = 10.0f / 55.0f;

    long long c = (long long)blockIdx.x * 4 + wave;
    const long long cs = (long long)gridDim.x * 4;

    for (; c < nChunks; c += cs) {
        const float4* __restrict__ src = in4 + c * 320;

        float4 v0 = src[lane];
        float4 v1 = src[lane + 64];
        float4 v2 = src[lane + 128];
        float4 v3 = src[lane + 192];
        float4 v4 = src[lane + 256];

        l4[lane]       = v0;
        l4[lane + 64]  = v1;
        l4[lane + 128] = v2;
        l4[lane + 192] = v3;
        l4[lane + 256] = v4;

        __syncthreads();  // stage visible before cross-lane reads

        const float4 a0 = l4[lane * 5 + 0];
        const float4 a1 = l4[lane * 5 + 1];
        const float4 a2 = l4[lane * 5 + 2];
        const float4 a3 = l4[lane * 5 + 3];
        const float4 a4 = l4[lane * 5 + 4];

        float s0 = a0.x * w0 + a0.y * w1 + a0.z * w2 + a0.w * w3
                 + a1.x * w4 + a1.y * w5 + a1.z * w6 + a1.w * w7
                 + a2.x * w8 + a2.y * w9;

        float s1 = a2.z * w0 + a2.w * w1
                 + a3.x * w2 + a3.y * w3 + a3.z * w4 + a3.w * w5
                 + a4.x * w6 + a4.y * w7 + a4.z * w8 + a4.w * w9;

        out2[c * 64 + lane] = make_float2(s0, s1);

        __syncthreads();  // reads done before next iteration overwrites
    }
}

extern "C" void kernel_launch(void* const* d_in, const int* in_sizes, int n_in,
                              void* d_out, int out_size, void* d_ws, size_t ws_size,
                              hipStream_t stream) {
    const float4* in4 = (const float4*)d_in[0];
    float2* out2 = (float2*)d_out;

    // in: 153,600,000 floats = 38,400,000 float4; 320 float4 per wave-chunk.
    long long nFloat4 = (long long)in_sizes[0] / 4;
    long long nChunks = nFloat4 / 320;  // = 120,000 (exact)

    int block = 256;  // 4 waves
    long long blocksNeeded = (nChunks + 3) / 4;
    int grid = (int)(blocksNeeded < 2048 ? blocksNeeded : 2048);

    ts_decaylinear_kernel<<<grid, block, 0, stream>>>(in4, out2, nChunks);
}